// Round 1
// baseline (884.147 us; speedup 1.0000x reference)
//
#include <hip/hip_runtime.h>
#include <hip/hip_bf16.h>

#define N_NODES 100000
#define N_EDGES 1000000
#define S_DIM 64
#define F_DIM 64
#define RBF_DIM 16
#define V_CH 16

#define EBLK 128
#define NBLK 128

__device__ __forceinline__ float silu_f(float x) {
    return x * (1.0f / (1.0f + __expf(-x)));
}

// ---------------- Edge kernel: h=silu(cat@W1+b1); h=silu(h@W2+b2); LN(ef+h) ----------------
__global__ __launch_bounds__(EBLK, 4) void edge_kernel(
    const float* __restrict__ ns, const float* __restrict__ ef,
    const float* __restrict__ dd, const int* __restrict__ src,
    const int* __restrict__ dst, const float* __restrict__ W1,
    const float* __restrict__ b1, const float* __restrict__ W2,
    const float* __restrict__ b2, const float* __restrict__ lng,
    const float* __restrict__ lnb, float* __restrict__ out)
{
    __shared__ float lds_h2[F_DIM][EBLK];  // 32 KB
    const int tid = threadIdx.x;
    const int e = blockIdx.x * EBLK + tid;
    const bool active = (e < N_EDGES);
    const int ec = active ? e : 0;

    const int si = src[ec];
    const int di = dst[ec];
    const float* hs = ns + (size_t)si * S_DIM;
    const float* hd = ns + (size_t)di * S_DIM;
    const float* he = ef + (size_t)ec * F_DIM;
    const float* hr = dd + (size_t)ec * RBF_DIM;

    float acc[F_DIM];
    #pragma unroll
    for (int j = 0; j < F_DIM; ++j) acc[j] = b1[j];

    // segment 0: node_scalars[src]  (rows 0..63 of W1)
    #pragma unroll 2
    for (int k = 0; k < S_DIM; ++k) {
        const float hk = hs[k];
        const float* w = W1 + (size_t)k * F_DIM;
        #pragma unroll
        for (int j = 0; j < F_DIM; ++j) acc[j] = fmaf(hk, w[j], acc[j]);
    }
    // segment 1: node_scalars[dst]  (rows 64..127)
    #pragma unroll 2
    for (int k = 0; k < S_DIM; ++k) {
        const float hk = hd[k];
        const float* w = W1 + (size_t)(S_DIM + k) * F_DIM;
        #pragma unroll
        for (int j = 0; j < F_DIM; ++j) acc[j] = fmaf(hk, w[j], acc[j]);
    }
    // segment 2: edge_feats  (rows 128..191)
    #pragma unroll 2
    for (int k = 0; k < F_DIM; ++k) {
        const float hk = he[k];
        const float* w = W1 + (size_t)(2 * S_DIM + k) * F_DIM;
        #pragma unroll
        for (int j = 0; j < F_DIM; ++j) acc[j] = fmaf(hk, w[j], acc[j]);
    }
    // segment 3: d (rbf)  (rows 192..207)
    #pragma unroll 2
    for (int k = 0; k < RBF_DIM; ++k) {
        const float hk = hr[k];
        const float* w = W1 + (size_t)(2 * S_DIM + F_DIM + k) * F_DIM;
        #pragma unroll
        for (int j = 0; j < F_DIM; ++j) acc[j] = fmaf(hk, w[j], acc[j]);
    }

    // silu -> LDS (per-thread private column; no barrier needed)
    #pragma unroll
    for (int j = 0; j < F_DIM; ++j) lds_h2[j][tid] = silu_f(acc[j]);

    // layer 2
    float acc2[F_DIM];
    #pragma unroll
    for (int j = 0; j < F_DIM; ++j) acc2[j] = b2[j];
    #pragma unroll 2
    for (int k = 0; k < F_DIM; ++k) {
        const float hk = lds_h2[k][tid];
        const float* w = W2 + (size_t)k * F_DIM;
        #pragma unroll
        for (int j = 0; j < F_DIM; ++j) acc2[j] = fmaf(hk, w[j], acc2[j]);
    }

    // silu + residual + layernorm
    float mean = 0.0f;
    #pragma unroll
    for (int j = 0; j < F_DIM; ++j) {
        float x = silu_f(acc2[j]) + he[j];
        acc2[j] = x;
        mean += x;
    }
    mean *= (1.0f / (float)F_DIM);
    float var = 0.0f;
    #pragma unroll
    for (int j = 0; j < F_DIM; ++j) {
        float dx = acc2[j] - mean;
        var += dx * dx;
    }
    var *= (1.0f / (float)F_DIM);
    const float rs = rsqrtf(var + 1e-5f);
    #pragma unroll
    for (int j = 0; j < F_DIM; ++j) {
        acc2[j] = (acc2[j] - mean) * rs * lng[j] + lnb[j];
    }

    if (active) {
        float* op = out + (size_t)e * F_DIM;
        #pragma unroll
        for (int i = 0; i < F_DIM / 4; ++i) {
            float4 v4 = make_float4(acc2[4 * i], acc2[4 * i + 1], acc2[4 * i + 2], acc2[4 * i + 3]);
            *reinterpret_cast<float4*>(op + 4 * i) = v4;
        }
    }
}

// ---------------- Node kernel: 3 stacked GVPs ----------------
// The only dynamic contraction index (h) multiplies UNIFORM weights -> s_load broadcast;
// per-lane vectors stay register-static. concat(s,sh) goes through LDS for the Ws matmul.
template <int UOUT, bool SIG>
__device__ __forceinline__ void gvp_step(
    float* __restrict__ s /*[64]*/, float* __restrict__ vv /*[48] in, [UOUT*3] out*/,
    const float* __restrict__ Wh, const float* __restrict__ Wu,
    const float* __restrict__ Ws, const float* __restrict__ bs,
    float (*cat)[NBLK], const int tid)
{
    // s -> cat[0..63]
    #pragma unroll
    for (int j = 0; j < 64; ++j) cat[j][tid] = s[j];

    float vu[UOUT * 3];
    #pragma unroll
    for (int i = 0; i < UOUT * 3; ++i) vu[i] = 0.0f;

    for (int h = 0; h < V_CH; ++h) {  // dynamic; Wh/Wu uniform
        float t0 = 0.0f, t1 = 0.0f, t2 = 0.0f;
        #pragma unroll
        for (int vi = 0; vi < V_CH; ++vi) {
            const float wv = Wh[vi * V_CH + h];
            t0 = fmaf(vv[vi * 3 + 0], wv, t0);
            t1 = fmaf(vv[vi * 3 + 1], wv, t1);
            t2 = fmaf(vv[vi * 3 + 2], wv, t2);
        }
        cat[64 + h][tid] = sqrtf(t0 * t0 + t1 * t1 + t2 * t2 + 1e-8f);  // sh
        #pragma unroll
        for (int u = 0; u < UOUT; ++u) {
            const float wu = Wu[h * UOUT + u];
            vu[u * 3 + 0] = fmaf(t0, wu, vu[u * 3 + 0]);
            vu[u * 3 + 1] = fmaf(t1, wu, vu[u * 3 + 1]);
            vu[u * 3 + 2] = fmaf(t2, wu, vu[u * 3 + 2]);
        }
    }

    // s_out = silu(cat @ Ws + bs)
    float acc[64];
    #pragma unroll
    for (int j = 0; j < 64; ++j) acc[j] = bs[j];
    #pragma unroll 2
    for (int k = 0; k < 64 + V_CH; ++k) {
        const float hk = cat[k][tid];
        const float* w = Ws + (size_t)k * 64;
        #pragma unroll
        for (int j = 0; j < 64; ++j) acc[j] = fmaf(hk, w[j], acc[j]);
    }
    #pragma unroll
    for (int j = 0; j < 64; ++j) s[j] = silu_f(acc[j]);

    // vector gate
    #pragma unroll
    for (int u = 0; u < UOUT; ++u) {
        const float a = vu[u * 3 + 0];
        const float b = vu[u * 3 + 1];
        const float c = vu[u * 3 + 2];
        const float vn = sqrtf(a * a + b * b + c * c + 1e-8f);
        const float g = SIG ? (1.0f / (1.0f + __expf(-vn))) : vn;
        vv[u * 3 + 0] = g * a;
        vv[u * 3 + 1] = g * b;
        vv[u * 3 + 2] = g * c;
    }
}

__global__ __launch_bounds__(NBLK, 2) void node_kernel(
    const float* __restrict__ ns, const float* __restrict__ pos,
    const float* __restrict__ vec,
    const float* __restrict__ Wh0, const float* __restrict__ Wu0,
    const float* __restrict__ Ws0, const float* __restrict__ bs0,
    const float* __restrict__ Wh1, const float* __restrict__ Wu1,
    const float* __restrict__ Ws1, const float* __restrict__ bs1,
    const float* __restrict__ Wh2, const float* __restrict__ Wu2,
    const float* __restrict__ Ws2, const float* __restrict__ bs2,
    float* __restrict__ outpos)
{
    __shared__ float cat[64 + V_CH][NBLK];  // 40 KB
    const int tid = threadIdx.x;
    const int n = blockIdx.x * NBLK + tid;
    const bool active = (n < N_NODES);
    const int nc = active ? n : 0;

    float s[64];
    {
        const float* p = ns + (size_t)nc * S_DIM;
        #pragma unroll
        for (int i = 0; i < 16; ++i) {
            float4 v4 = *reinterpret_cast<const float4*>(p + 4 * i);
            s[4 * i] = v4.x; s[4 * i + 1] = v4.y; s[4 * i + 2] = v4.z; s[4 * i + 3] = v4.w;
        }
    }
    float vv[48];
    {
        const float* p = vec + (size_t)nc * (V_CH * 3);
        #pragma unroll
        for (int i = 0; i < 12; ++i) {
            float4 v4 = *reinterpret_cast<const float4*>(p + 4 * i);
            vv[4 * i] = v4.x; vv[4 * i + 1] = v4.y; vv[4 * i + 2] = v4.z; vv[4 * i + 3] = v4.w;
        }
    }

    gvp_step<V_CH, true>(s, vv, Wh0, Wu0, Ws0, bs0, cat, tid);
    gvp_step<V_CH, true>(s, vv, Wh1, Wu1, Ws1, bs1, cat, tid);
    gvp_step<1, false>(s, vv, Wh2, Wu2, Ws2, bs2, cat, tid);

    if (active) {
        outpos[(size_t)n * 3 + 0] = pos[(size_t)n * 3 + 0] + vv[0];
        outpos[(size_t)n * 3 + 1] = pos[(size_t)n * 3 + 1] + vv[1];
        outpos[(size_t)n * 3 + 2] = pos[(size_t)n * 3 + 2] + vv[2];
    }
}

extern "C" void kernel_launch(void* const* d_in, const int* in_sizes, int n_in,
                              void* d_out, int out_size, void* d_ws, size_t ws_size,
                              hipStream_t stream) {
    const float* ns  = (const float*)d_in[0];
    const float* pos = (const float*)d_in[1];
    const float* vec = (const float*)d_in[2];
    const float* ef  = (const float*)d_in[3];
    const float* dd  = (const float*)d_in[4];
    const int*   src = (const int*)d_in[5];
    const int*   dst = (const int*)d_in[6];
    const float* W1  = (const float*)d_in[7];
    const float* b1  = (const float*)d_in[8];
    const float* W2  = (const float*)d_in[9];
    const float* b2  = (const float*)d_in[10];
    const float* lng = (const float*)d_in[11];
    const float* lnb = (const float*)d_in[12];
    const float* Wh0 = (const float*)d_in[13];
    const float* Wu0 = (const float*)d_in[14];
    const float* Ws0 = (const float*)d_in[15];
    const float* bs0 = (const float*)d_in[16];
    const float* Wh1 = (const float*)d_in[17];
    const float* Wu1 = (const float*)d_in[18];
    const float* Ws1 = (const float*)d_in[19];
    const float* bs1 = (const float*)d_in[20];
    const float* Wh2 = (const float*)d_in[21];
    const float* Wu2 = (const float*)d_in[22];
    const float* Ws2 = (const float*)d_in[23];
    const float* bs2 = (const float*)d_in[24];

    float* out     = (float*)d_out;
    float* out_pos = out + (size_t)N_EDGES * F_DIM;

    edge_kernel<<<(N_EDGES + EBLK - 1) / EBLK, EBLK, 0, stream>>>(
        ns, ef, dd, src, dst, W1, b1, W2, b2, lng, lnb, out);
    node_kernel<<<(N_NODES + NBLK - 1) / NBLK, NBLK, 0, stream>>>(
        ns, pos, vec, Wh0, Wu0, Ws0, bs0, Wh1, Wu1, Ws1, bs1, Wh2, Wu2, Ws2, bs2, out_pos);
}

// Round 2
// 620.939 us; speedup vs baseline: 1.4239x; 1.4239x over previous
//
#include <hip/hip_runtime.h>
#include <hip/hip_bf16.h>

#define N_NODES 100000
#define N_EDGES 1000000
#define S_DIM 64
#define F_DIM 64
#define RBF_DIM 16
#define V_CH 16

typedef __attribute__((ext_vector_type(4))) float f32x4;
typedef __attribute__((ext_vector_type(8))) short bf16x8;

#define NBLK 128
#define TILES_PER_WAVE 5
#define EDGE_GRID 3125   // 3125 blocks * 4 waves * 5 tiles * 16 edges = 1,000,000 exactly

__device__ __forceinline__ float silu_f(float x) {
    return x * (1.0f / (1.0f + __expf(-x)));
}

// round-to-nearest-even f32 -> bf16 bits (finite inputs)
__device__ __forceinline__ ushort f2bf(float x) {
    uint u = __float_as_uint(x);
    uint r = (u + 0x7fffu + ((u >> 16) & 1u)) >> 16;
    return (ushort)r;
}

__device__ __forceinline__ bf16x8 load8_bf(const float* p) {
    const float4 u = *reinterpret_cast<const float4*>(p);
    const float4 v = *reinterpret_cast<const float4*>(p + 4);
    bf16x8 r;
    r[0] = (short)f2bf(u.x); r[1] = (short)f2bf(u.y);
    r[2] = (short)f2bf(u.z); r[3] = (short)f2bf(u.w);
    r[4] = (short)f2bf(v.x); r[5] = (short)f2bf(v.y);
    r[6] = (short)f2bf(v.z); r[7] = (short)f2bf(v.w);
    return r;
}

// ---------------- Edge kernel (MFMA bf16) ----------------
// Per wave: 16-edge x 64-out tile. A-frag: row=lane&15, k=(lane>>4)*8+j.
// C/D: col=lane&15 (+16*nn), row=4*(lane>>4)+reg  [m89-verified layout].
__global__ __launch_bounds__(256, 3) void edge_kernel(
    const float* __restrict__ ns, const float* __restrict__ ef,
    const float* __restrict__ dd, const int* __restrict__ src,
    const int* __restrict__ dst, const float* __restrict__ W1,
    const float* __restrict__ b1, const float* __restrict__ W2,
    const float* __restrict__ b2, const float* __restrict__ lng,
    const float* __restrict__ lnb, float* __restrict__ out)
{
    // frag-major weight tiles: consecutive lanes -> consecutive 16B => conflict-free b128
    __shared__ __align__(16) ushort b1f[7][4][64][8];   // 28672 B
    __shared__ __align__(16) ushort b2f[2][4][64][8];   //  8192 B
    __shared__ __align__(16) float  h2buf[4][16][68];   // 17408 B (stride 68: 2-way bank alias, 16B-aligned rows)

    const int tid  = threadIdx.x;
    const int lane = tid & 63;
    const int wid  = tid >> 6;
    const int l15  = lane & 15;
    const int g    = lane >> 4;

    // ---- one-time weight swizzle to LDS (256 threads cooperative) ----
    {
        const int fl  = tid & 63;
        const int fnn = tid >> 6;                 // 0..3
        const int col = 16 * fnn + (fl & 15);
        const int krow = (fl >> 4) << 3;
        #pragma unroll
        for (int kk = 0; kk < 7; ++kk) {
            const int k0 = 32 * kk + krow;
            bf16x8 w;
            #pragma unroll
            for (int j = 0; j < 8; ++j) {
                const int k = k0 + j;
                w[j] = (k < 208) ? (short)f2bf(W1[k * 64 + col]) : (short)0;
            }
            *reinterpret_cast<bf16x8*>(&b1f[kk][fnn][fl][0]) = w;
        }
        #pragma unroll
        for (int kk = 0; kk < 2; ++kk) {
            const int k0 = 32 * kk + krow;
            bf16x8 w;
            #pragma unroll
            for (int j = 0; j < 8; ++j) w[j] = (short)f2bf(W2[(k0 + j) * 64 + col]);
            *reinterpret_cast<bf16x8*>(&b2f[kk][fnn][fl][0]) = w;
        }
    }
    __syncthreads();

    // per-lane broadcastable constants (cached)
    float b1c[4], b2c[4], lgc[4], lbc[4];
    #pragma unroll
    for (int nn = 0; nn < 4; ++nn) {
        b1c[nn] = b1[16 * nn + l15];
        b2c[nn] = b2[16 * nn + l15];
        lgc[nn] = lng[16 * nn + l15];
        lbc[nn] = lnb[16 * nn + l15];
    }

    for (int t = 0; t < TILES_PER_WAVE; ++t) {
        const int tile  = (blockIdx.x * 4 + wid) * TILES_PER_WAVE + t;
        const int ebase = tile * 16;
        const int erow  = ebase + l15;

        const int si = src[erow];
        const int di = dst[erow];
        const float* ps = ns + (size_t)si * 64;
        const float* pd = ns + (size_t)di * 64;
        const float* pe = ef + (size_t)erow * 64;
        const float* pr = dd + (size_t)erow * 16;

        // ---- gather A-fragments straight from global (8-elem segments never cross sources) ----
        bf16x8 a[7];
        a[0] = load8_bf(ps + 8 * g);
        a[1] = load8_bf(ps + 32 + 8 * g);
        a[2] = load8_bf(pd + 8 * g);
        a[3] = load8_bf(pd + 32 + 8 * g);
        a[4] = load8_bf(pe + 8 * g);
        a[5] = load8_bf(pe + 32 + 8 * g);
        {
            bf16x8 z = {0, 0, 0, 0, 0, 0, 0, 0};
            if (g < 2) z = load8_bf(pr + 8 * g);   // k 192..207 = rbf, 208..223 = pad
            a[6] = z;
        }

        // ---- layer 1: 7 K-chunks x 4 N-tiles ----
        f32x4 acc[4];
        #pragma unroll
        for (int nn = 0; nn < 4; ++nn) acc[nn] = (f32x4){0.f, 0.f, 0.f, 0.f};
        #pragma unroll
        for (int kk = 0; kk < 7; ++kk) {
            #pragma unroll
            for (int nn = 0; nn < 4; ++nn) {
                const bf16x8 b = *reinterpret_cast<const bf16x8*>(&b1f[kk][nn][lane][0]);
                acc[nn] = __builtin_amdgcn_mfma_f32_16x16x32_bf16(a[kk], b, acc[nn], 0, 0, 0);
            }
        }

        // ---- silu -> LDS (C-layout scatter), same-wave only, no barrier ----
        #pragma unroll
        for (int nn = 0; nn < 4; ++nn) {
            #pragma unroll
            for (int r = 0; r < 4; ++r) {
                h2buf[wid][4 * g + r][16 * nn + l15] = silu_f(acc[nn][r] + b1c[nn]);
            }
        }

        // ---- A2 fragments from LDS ----
        bf16x8 a2[2];
        #pragma unroll
        for (int kk = 0; kk < 2; ++kk) {
            a2[kk] = load8_bf(&h2buf[wid][l15][32 * kk + 8 * g]);
        }

        // ---- layer 2 ----
        f32x4 acc2[4];
        #pragma unroll
        for (int nn = 0; nn < 4; ++nn) acc2[nn] = (f32x4){0.f, 0.f, 0.f, 0.f};
        #pragma unroll
        for (int kk = 0; kk < 2; ++kk) {
            #pragma unroll
            for (int nn = 0; nn < 4; ++nn) {
                const bf16x8 b = *reinterpret_cast<const bf16x8*>(&b2f[kk][nn][lane][0]);
                acc2[nn] = __builtin_amdgcn_mfma_f32_16x16x32_bf16(a2[kk], b, acc2[nn], 0, 0, 0);
            }
        }

        // ---- epilogue: silu + residual + layernorm (rows live in 16-lane groups) ----
        float x[4][4];
        #pragma unroll
        for (int nn = 0; nn < 4; ++nn) {
            #pragma unroll
            for (int r = 0; r < 4; ++r) {
                const size_t row = (size_t)(ebase + 4 * g + r);
                x[nn][r] = silu_f(acc2[nn][r] + b2c[nn]) + ef[row * 64 + 16 * nn + l15];
            }
        }
        float mean[4], rsd[4];
        #pragma unroll
        for (int r = 0; r < 4; ++r) {
            float s = x[0][r] + x[1][r] + x[2][r] + x[3][r];
            s += __shfl_xor(s, 1); s += __shfl_xor(s, 2);
            s += __shfl_xor(s, 4); s += __shfl_xor(s, 8);
            mean[r] = s * (1.0f / 64.0f);
        }
        #pragma unroll
        for (int r = 0; r < 4; ++r) {
            float v = 0.f;
            #pragma unroll
            for (int nn = 0; nn < 4; ++nn) {
                const float dx = x[nn][r] - mean[r];
                v += dx * dx;
            }
            v += __shfl_xor(v, 1); v += __shfl_xor(v, 2);
            v += __shfl_xor(v, 4); v += __shfl_xor(v, 8);
            rsd[r] = rsqrtf(v * (1.0f / 64.0f) + 1e-5f);
        }
        #pragma unroll
        for (int nn = 0; nn < 4; ++nn) {
            #pragma unroll
            for (int r = 0; r < 4; ++r) {
                const size_t row = (size_t)(ebase + 4 * g + r);
                out[row * 64 + 16 * nn + l15] =
                    (x[nn][r] - mean[r]) * rsd[r] * lgc[nn] + lbc[nn];
            }
        }
    }
}

// ---------------- Node kernel: 3 stacked GVPs (unchanged) ----------------
template <int UOUT, bool SIG>
__device__ __forceinline__ void gvp_step(
    float* __restrict__ s, float* __restrict__ vv,
    const float* __restrict__ Wh, const float* __restrict__ Wu,
    const float* __restrict__ Ws, const float* __restrict__ bs,
    float (*cat)[NBLK], const int tid)
{
    #pragma unroll
    for (int j = 0; j < 64; ++j) cat[j][tid] = s[j];

    float vu[UOUT * 3];
    #pragma unroll
    for (int i = 0; i < UOUT * 3; ++i) vu[i] = 0.0f;

    for (int h = 0; h < V_CH; ++h) {
        float t0 = 0.0f, t1 = 0.0f, t2 = 0.0f;
        #pragma unroll
        for (int vi = 0; vi < V_CH; ++vi) {
            const float wv = Wh[vi * V_CH + h];
            t0 = fmaf(vv[vi * 3 + 0], wv, t0);
            t1 = fmaf(vv[vi * 3 + 1], wv, t1);
            t2 = fmaf(vv[vi * 3 + 2], wv, t2);
        }
        cat[64 + h][tid] = sqrtf(t0 * t0 + t1 * t1 + t2 * t2 + 1e-8f);
        #pragma unroll
        for (int u = 0; u < UOUT; ++u) {
            const float wu = Wu[h * UOUT + u];
            vu[u * 3 + 0] = fmaf(t0, wu, vu[u * 3 + 0]);
            vu[u * 3 + 1] = fmaf(t1, wu, vu[u * 3 + 1]);
            vu[u * 3 + 2] = fmaf(t2, wu, vu[u * 3 + 2]);
        }
    }

    float acc[64];
    #pragma unroll
    for (int j = 0; j < 64; ++j) acc[j] = bs[j];
    #pragma unroll 2
    for (int k = 0; k < 64 + V_CH; ++k) {
        const float hk = cat[k][tid];
        const float* w = Ws + (size_t)k * 64;
        #pragma unroll
        for (int j = 0; j < 64; ++j) acc[j] = fmaf(hk, w[j], acc[j]);
    }
    #pragma unroll
    for (int j = 0; j < 64; ++j) s[j] = silu_f(acc[j]);

    #pragma unroll
    for (int u = 0; u < UOUT; ++u) {
        const float a = vu[u * 3 + 0];
        const float b = vu[u * 3 + 1];
        const float c = vu[u * 3 + 2];
        const float vn = sqrtf(a * a + b * b + c * c + 1e-8f);
        const float gt = SIG ? (1.0f / (1.0f + __expf(-vn))) : vn;
        vv[u * 3 + 0] = gt * a;
        vv[u * 3 + 1] = gt * b;
        vv[u * 3 + 2] = gt * c;
    }
}

__global__ __launch_bounds__(NBLK, 2) void node_kernel(
    const float* __restrict__ ns, const float* __restrict__ pos,
    const float* __restrict__ vec,
    const float* __restrict__ Wh0, const float* __restrict__ Wu0,
    const float* __restrict__ Ws0, const float* __restrict__ bs0,
    const float* __restrict__ Wh1, const float* __restrict__ Wu1,
    const float* __restrict__ Ws1, const float* __restrict__ bs1,
    const float* __restrict__ Wh2, const float* __restrict__ Wu2,
    const float* __restrict__ Ws2, const float* __restrict__ bs2,
    float* __restrict__ outpos)
{
    __shared__ float cat[64 + V_CH][NBLK];
    const int tid = threadIdx.x;
    const int n = blockIdx.x * NBLK + tid;
    const bool active = (n < N_NODES);
    const int nc = active ? n : 0;

    float s[64];
    {
        const float* p = ns + (size_t)nc * S_DIM;
        #pragma unroll
        for (int i = 0; i < 16; ++i) {
            float4 v4 = *reinterpret_cast<const float4*>(p + 4 * i);
            s[4 * i] = v4.x; s[4 * i + 1] = v4.y; s[4 * i + 2] = v4.z; s[4 * i + 3] = v4.w;
        }
    }
    float vv[48];
    {
        const float* p = vec + (size_t)nc * (V_CH * 3);
        #pragma unroll
        for (int i = 0; i < 12; ++i) {
            float4 v4 = *reinterpret_cast<const float4*>(p + 4 * i);
            vv[4 * i] = v4.x; vv[4 * i + 1] = v4.y; vv[4 * i + 2] = v4.z; vv[4 * i + 3] = v4.w;
        }
    }

    gvp_step<V_CH, true>(s, vv, Wh0, Wu0, Ws0, bs0, cat, tid);
    gvp_step<V_CH, true>(s, vv, Wh1, Wu1, Ws1, bs1, cat, tid);
    gvp_step<1, false>(s, vv, Wh2, Wu2, Ws2, bs2, cat, tid);

    if (active) {
        outpos[(size_t)n * 3 + 0] = pos[(size_t)n * 3 + 0] + vv[0];
        outpos[(size_t)n * 3 + 1] = pos[(size_t)n * 3 + 1] + vv[1];
        outpos[(size_t)n * 3 + 2] = pos[(size_t)n * 3 + 2] + vv[2];
    }
}

extern "C" void kernel_launch(void* const* d_in, const int* in_sizes, int n_in,
                              void* d_out, int out_size, void* d_ws, size_t ws_size,
                              hipStream_t stream) {
    const float* ns  = (const float*)d_in[0];
    const float* pos = (const float*)d_in[1];
    const float* vec = (const float*)d_in[2];
    const float* ef  = (const float*)d_in[3];
    const float* dd  = (const float*)d_in[4];
    const int*   src = (const int*)d_in[5];
    const int*   dst = (const int*)d_in[6];
    const float* W1  = (const float*)d_in[7];
    const float* b1  = (const float*)d_in[8];
    const float* W2  = (const float*)d_in[9];
    const float* b2  = (const float*)d_in[10];
    const float* lng = (const float*)d_in[11];
    const float* lnb = (const float*)d_in[12];
    const float* Wh0 = (const float*)d_in[13];
    const float* Wu0 = (const float*)d_in[14];
    const float* Ws0 = (const float*)d_in[15];
    const float* bs0 = (const float*)d_in[16];
    const float* Wh1 = (const float*)d_in[17];
    const float* Wu1 = (const float*)d_in[18];
    const float* Ws1 = (const float*)d_in[19];
    const float* bs1 = (const float*)d_in[20];
    const float* Wh2 = (const float*)d_in[21];
    const float* Wu2 = (const float*)d_in[22];
    const float* Ws2 = (const float*)d_in[23];
    const float* bs2 = (const float*)d_in[24];

    float* out     = (float*)d_out;
    float* out_pos = out + (size_t)N_EDGES * F_DIM;

    edge_kernel<<<EDGE_GRID, 256, 0, stream>>>(
        ns, ef, dd, src, dst, W1, b1, W2, b2, lng, lnb, out);
    node_kernel<<<(N_NODES + NBLK - 1) / NBLK, NBLK, 0, stream>>>(
        ns, pos, vec, Wh0, Wu0, Ws0, bs0, Wh1, Wu1, Ws1, bs1, Wh2, Wu2, Ws2, bs2, out_pos);
}

// Round 4
// 311.666 us; speedup vs baseline: 2.8368x; 1.9923x over previous
//
#include <hip/hip_runtime.h>
#include <hip/hip_bf16.h>

#define N_NODES 100000
#define N_EDGES 1000000
#define S_DIM 64
#define F_DIM 64
#define RBF_DIM 16
#define V_CH 16

typedef __attribute__((ext_vector_type(4))) float f32x4;
typedef __attribute__((ext_vector_type(8))) short bf16x8;

#define NBLK 128
#define TPW 5            // tiles per wave
#define EDGE_GRID 3125   // 3125 * 4 waves * 5 tiles * 16 edges = 1,000,000 exactly

// compiler-level memory barrier: forbids reordering LDS writes/reads across
// phase boundaries (TBAA must not break same-wave producer/consumer through LDS)
#define LDS_FENCE() asm volatile("" ::: "memory")

__device__ __forceinline__ float silu_f(float x) {
    return x * (1.0f / (1.0f + __expf(-x)));
}

// round-to-nearest-even f32 -> bf16 bits (finite inputs)
__device__ __forceinline__ ushort f2bf(float x) {
    uint u = __float_as_uint(x);
    uint r = (u + 0x7fffu + ((u >> 16) & 1u)) >> 16;
    return (ushort)r;
}

__device__ __forceinline__ float4 ld4(const float* p) {
    return *reinterpret_cast<const float4*>(p);
}

__device__ __forceinline__ bf16x8 pack8(float4 u, float4 v) {
    bf16x8 r;
    r[0] = (short)f2bf(u.x); r[1] = (short)f2bf(u.y);
    r[2] = (short)f2bf(u.z); r[3] = (short)f2bf(u.w);
    r[4] = (short)f2bf(v.x); r[5] = (short)f2bf(v.y);
    r[6] = (short)f2bf(v.z); r[7] = (short)f2bf(v.w);
    return r;
}

struct Raw { float4 v[14]; };

// ---------------- Edge kernel (MFMA bf16, prefetched) ----------------
// Per wave: 16-edge x 64-out tile. A-frag: row=lane&15, k=(lane>>4)*8+j.
// C/D: col=lane&15 (+16*nn), row=4*(lane>>4)+reg  [m89-verified layout].
__global__ __launch_bounds__(256, 2) void edge_kernel(
    const float* __restrict__ ns, const float* __restrict__ ef,
    const float* __restrict__ dd, const int* __restrict__ src,
    const int* __restrict__ dst, const float* __restrict__ W1,
    const float* __restrict__ b1, const float* __restrict__ W2,
    const float* __restrict__ b2, const float* __restrict__ lng,
    const float* __restrict__ lnb, float* __restrict__ out)
{
    __shared__ __align__(16) ushort b1f[7][4][64][8];   // 28672 B
    __shared__ __align__(16) ushort b2f[2][4][64][8];   //  8192 B
    __shared__ __align__(16) float  h2buf[4][16][68];   // 17408 B (per-wave scratch)

    const int tid  = threadIdx.x;
    const int lane = tid & 63;
    const int wid  = tid >> 6;
    const int l15  = lane & 15;
    const int g    = lane >> 4;

    // ---- one-time weight swizzle to LDS (bf16x8 both sides; sealed by syncthreads) ----
    {
        const int fl  = tid & 63;
        const int fnn = tid >> 6;
        const int col = 16 * fnn + (fl & 15);
        const int krow = (fl >> 4) << 3;
        #pragma unroll
        for (int kk = 0; kk < 7; ++kk) {
            const int k0 = 32 * kk + krow;
            bf16x8 w;
            #pragma unroll
            for (int j = 0; j < 8; ++j) {
                const int k = k0 + j;
                w[j] = (k < 208) ? (short)f2bf(W1[k * 64 + col]) : (short)0;
            }
            *reinterpret_cast<bf16x8*>(&b1f[kk][fnn][fl][0]) = w;
        }
        #pragma unroll
        for (int kk = 0; kk < 2; ++kk) {
            const int k0 = 32 * kk + krow;
            bf16x8 w;
            #pragma unroll
            for (int j = 0; j < 8; ++j) w[j] = (short)f2bf(W2[(k0 + j) * 64 + col]);
            *reinterpret_cast<bf16x8*>(&b2f[kk][fnn][fl][0]) = w;
        }
    }
    __syncthreads();

    float b1c[4], b2c[4], lgc[4], lbc[4];
    #pragma unroll
    for (int nn = 0; nn < 4; ++nn) {
        b1c[nn] = b1[16 * nn + l15];
        b2c[nn] = b2[16 * nn + l15];
        lgc[nn] = lng[16 * nn + l15];
        lbc[nn] = lnb[16 * nn + l15];
    }

    const int wtile0 = (blockIdx.x * 4 + wid) * TPW;

    // ---- all tile indices up-front ----
    int sis[TPW], dis[TPW];
    #pragma unroll
    for (int t = 0; t < TPW; ++t) {
        const int erow = (wtile0 + t) * 16 + l15;
        sis[t] = src[erow];
        dis[t] = dst[erow];
    }

    float (*hb)[68] = h2buf[wid];   // [16][68] per-wave scratch

    // ---- prefetch loader (t compile-time via unroll => static sis/dis index) ----
    auto load_raw = [&](Raw& r, int t) {
        const int erow = (wtile0 + t) * 16 + l15;
        const float* ps = ns + (size_t)sis[t] * 64 + 8 * g;
        const float* pd = ns + (size_t)dis[t] * 64 + 8 * g;
        const float* pe = ef + (size_t)erow * 64 + 8 * g;
        const float* pr = dd + (size_t)erow * 16 + 8 * g;
        r.v[0] = ld4(ps);       r.v[1] = ld4(ps + 4);
        r.v[2] = ld4(ps + 32);  r.v[3] = ld4(ps + 36);
        r.v[4] = ld4(pd);       r.v[5] = ld4(pd + 4);
        r.v[6] = ld4(pd + 32);  r.v[7] = ld4(pd + 36);
        r.v[8] = ld4(pe);       r.v[9] = ld4(pe + 4);
        r.v[10] = ld4(pe + 32); r.v[11] = ld4(pe + 36);
        if (g < 2) { r.v[12] = ld4(pr); r.v[13] = ld4(pr + 4); }
        else { r.v[12] = make_float4(0.f,0.f,0.f,0.f); r.v[13] = make_float4(0.f,0.f,0.f,0.f); }
    };

    auto process = [&](const Raw& r, int t) {
        const int ebase = (wtile0 + t) * 16;

        bf16x8 a0 = pack8(r.v[0], r.v[1]);
        bf16x8 a1 = pack8(r.v[2], r.v[3]);
        bf16x8 a2f = pack8(r.v[4], r.v[5]);
        bf16x8 a3 = pack8(r.v[6], r.v[7]);
        bf16x8 a4 = pack8(r.v[8], r.v[9]);
        bf16x8 a5 = pack8(r.v[10], r.v[11]);
        bf16x8 a6 = pack8(r.v[12], r.v[13]);
        const float4 pef0 = r.v[8], pef1 = r.v[9], pef2 = r.v[10], pef3 = r.v[11];

        // ---- layer 1 (register-only) ----
        f32x4 acc[4];
        #pragma unroll
        for (int nn = 0; nn < 4; ++nn) acc[nn] = (f32x4){0.f, 0.f, 0.f, 0.f};
        #pragma unroll
        for (int nn = 0; nn < 4; ++nn) {
            acc[nn] = __builtin_amdgcn_mfma_f32_16x16x32_bf16(a0, *reinterpret_cast<const bf16x8*>(&b1f[0][nn][lane][0]), acc[nn], 0, 0, 0);
            acc[nn] = __builtin_amdgcn_mfma_f32_16x16x32_bf16(a1, *reinterpret_cast<const bf16x8*>(&b1f[1][nn][lane][0]), acc[nn], 0, 0, 0);
            acc[nn] = __builtin_amdgcn_mfma_f32_16x16x32_bf16(a2f, *reinterpret_cast<const bf16x8*>(&b1f[2][nn][lane][0]), acc[nn], 0, 0, 0);
            acc[nn] = __builtin_amdgcn_mfma_f32_16x16x32_bf16(a3, *reinterpret_cast<const bf16x8*>(&b1f[3][nn][lane][0]), acc[nn], 0, 0, 0);
            acc[nn] = __builtin_amdgcn_mfma_f32_16x16x32_bf16(a4, *reinterpret_cast<const bf16x8*>(&b1f[4][nn][lane][0]), acc[nn], 0, 0, 0);
            acc[nn] = __builtin_amdgcn_mfma_f32_16x16x32_bf16(a5, *reinterpret_cast<const bf16x8*>(&b1f[5][nn][lane][0]), acc[nn], 0, 0, 0);
            acc[nn] = __builtin_amdgcn_mfma_f32_16x16x32_bf16(a6, *reinterpret_cast<const bf16x8*>(&b1f[6][nn][lane][0]), acc[nn], 0, 0, 0);
        }

        // ---- h2 -> LDS (scalar f32, C-layout), read back A2 frags (scalar) ----
        LDS_FENCE();   // WAR vs previous tile's store-phase reads
        #pragma unroll
        for (int nn = 0; nn < 4; ++nn)
            #pragma unroll
            for (int rr = 0; rr < 4; ++rr)
                hb[4 * g + rr][16 * nn + l15] = silu_f(acc[nn][rr] + b1c[nn]);
        LDS_FENCE();   // RAW: writes above feed cross-lane reads below
        bf16x8 q0, q1;
        #pragma unroll
        for (int j = 0; j < 8; ++j) {
            q0[j] = (short)f2bf(hb[l15][8 * g + j]);
            q1[j] = (short)f2bf(hb[l15][32 + 8 * g + j]);
        }
        LDS_FENCE();   // WAR: ef writes below must not pass reads above

        // ---- ef residual staging (scalar writes); layer-2 MFMAs overlap (register-only) ----
        #pragma unroll
        for (int j = 0; j < 4; ++j) {
            hb[l15][8 * g + j]          = (&pef0.x)[j];
            hb[l15][8 * g + 4 + j]      = (&pef1.x)[j];
            hb[l15][32 + 8 * g + j]     = (&pef2.x)[j];
            hb[l15][32 + 8 * g + 4 + j] = (&pef3.x)[j];
        }

        f32x4 acc2[4];
        #pragma unroll
        for (int nn = 0; nn < 4; ++nn) acc2[nn] = (f32x4){0.f, 0.f, 0.f, 0.f};
        #pragma unroll
        for (int nn = 0; nn < 4; ++nn) {
            acc2[nn] = __builtin_amdgcn_mfma_f32_16x16x32_bf16(q0, *reinterpret_cast<const bf16x8*>(&b2f[0][nn][lane][0]), acc2[nn], 0, 0, 0);
            acc2[nn] = __builtin_amdgcn_mfma_f32_16x16x32_bf16(q1, *reinterpret_cast<const bf16x8*>(&b2f[1][nn][lane][0]), acc2[nn], 0, 0, 0);
        }

        LDS_FENCE();   // RAW: ef writes feed cross-lane residual reads
        float x[4][4];
        #pragma unroll
        for (int nn = 0; nn < 4; ++nn)
            #pragma unroll
            for (int rr = 0; rr < 4; ++rr)
                x[nn][rr] = silu_f(acc2[nn][rr] + b2c[nn]) + hb[4 * g + rr][16 * nn + l15];

        // ---- layernorm (row lives in a 16-lane group) ----
        float mean[4], rsd[4];
        #pragma unroll
        for (int rr = 0; rr < 4; ++rr) {
            float s = x[0][rr] + x[1][rr] + x[2][rr] + x[3][rr];
            s += __shfl_xor(s, 1); s += __shfl_xor(s, 2);
            s += __shfl_xor(s, 4); s += __shfl_xor(s, 8);
            mean[rr] = s * (1.0f / 64.0f);
        }
        #pragma unroll
        for (int rr = 0; rr < 4; ++rr) {
            float v = 0.f;
            #pragma unroll
            for (int nn = 0; nn < 4; ++nn) {
                const float dx = x[nn][rr] - mean[rr];
                v += dx * dx;
            }
            v += __shfl_xor(v, 1); v += __shfl_xor(v, 2);
            v += __shfl_xor(v, 4); v += __shfl_xor(v, 8);
            rsd[rr] = rsqrtf(v * (1.0f / 64.0f) + 1e-5f);
        }

        LDS_FENCE();   // WAR: normalized writes must not pass residual reads
        #pragma unroll
        for (int nn = 0; nn < 4; ++nn)
            #pragma unroll
            for (int rr = 0; rr < 4; ++rr)
                hb[4 * g + rr][16 * nn + l15] =
                    (x[nn][rr] - mean[rr]) * rsd[rr] * lgc[nn] + lbc[nn];
        LDS_FENCE();   // RAW: normalized writes feed cross-lane store reads

        // ---- transpose read (scalar) -> full-line float4 global stores ----
        float* obase = out + (size_t)ebase * 64;
        #pragma unroll
        for (int j = 0; j < 4; ++j) {
            const float* hr = &hb[4 * j + g][4 * l15];
            const float4 o = make_float4(hr[0], hr[1], hr[2], hr[3]);
            *reinterpret_cast<float4*>(obase + (size_t)(4 * j + g) * 64 + 4 * l15) = o;
        }
    };

    // ---- ping-pong prefetch pipeline ----
    Raw rA, rB;
    load_raw(rA, 0);
    #pragma unroll
    for (int t = 0; t < TPW; ++t) {
        if (t & 1) {
            if (t < TPW - 1) load_raw(rA, t + 1);
            process(rB, t);
        } else {
            if (t < TPW - 1) load_raw(rB, t + 1);
            process(rA, t);
        }
    }
}

// ---------------- Node kernel: 3 stacked GVPs (unchanged) ----------------
template <int UOUT, bool SIG>
__device__ __forceinline__ void gvp_step(
    float* __restrict__ s, float* __restrict__ vv,
    const float* __restrict__ Wh, const float* __restrict__ Wu,
    const float* __restrict__ Ws, const float* __restrict__ bs,
    float (*cat)[NBLK], const int tid)
{
    #pragma unroll
    for (int j = 0; j < 64; ++j) cat[j][tid] = s[j];

    float vu[UOUT * 3];
    #pragma unroll
    for (int i = 0; i < UOUT * 3; ++i) vu[i] = 0.0f;

    for (int h = 0; h < V_CH; ++h) {
        float t0 = 0.0f, t1 = 0.0f, t2 = 0.0f;
        #pragma unroll
        for (int vi = 0; vi < V_CH; ++vi) {
            const float wv = Wh[vi * V_CH + h];
            t0 = fmaf(vv[vi * 3 + 0], wv, t0);
            t1 = fmaf(vv[vi * 3 + 1], wv, t1);
            t2 = fmaf(vv[vi * 3 + 2], wv, t2);
        }
        cat[64 + h][tid] = sqrtf(t0 * t0 + t1 * t1 + t2 * t2 + 1e-8f);
        #pragma unroll
        for (int u = 0; u < UOUT; ++u) {
            const float wu = Wu[h * UOUT + u];
            vu[u * 3 + 0] = fmaf(t0, wu, vu[u * 3 + 0]);
            vu[u * 3 + 1] = fmaf(t1, wu, vu[u * 3 + 1]);
            vu[u * 3 + 2] = fmaf(t2, wu, vu[u * 3 + 2]);
        }
    }

    float acc[64];
    #pragma unroll
    for (int j = 0; j < 64; ++j) acc[j] = bs[j];
    #pragma unroll 2
    for (int k = 0; k < 64 + V_CH; ++k) {
        const float hk = cat[k][tid];
        const float* w = Ws + (size_t)k * 64;
        #pragma unroll
        for (int j = 0; j < 64; ++j) acc[j] = fmaf(hk, w[j], acc[j]);
    }
    #pragma unroll
    for (int j = 0; j < 64; ++j) s[j] = silu_f(acc[j]);

    #pragma unroll
    for (int u = 0; u < UOUT; ++u) {
        const float a = vu[u * 3 + 0];
        const float b = vu[u * 3 + 1];
        const float c = vu[u * 3 + 2];
        const float vn = sqrtf(a * a + b * b + c * c + 1e-8f);
        const float gt = SIG ? (1.0f / (1.0f + __expf(-vn))) : vn;
        vv[u * 3 + 0] = gt * a;
        vv[u * 3 + 1] = gt * b;
        vv[u * 3 + 2] = gt * c;
    }
}

__global__ __launch_bounds__(NBLK, 2) void node_kernel(
    const float* __restrict__ ns, const float* __restrict__ pos,
    const float* __restrict__ vec,
    const float* __restrict__ Wh0, const float* __restrict__ Wu0,
    const float* __restrict__ Ws0, const float* __restrict__ bs0,
    const float* __restrict__ Wh1, const float* __restrict__ Wu1,
    const float* __restrict__ Ws1, const float* __restrict__ bs1,
    const float* __restrict__ Wh2, const float* __restrict__ Wu2,
    const float* __restrict__ Ws2, const float* __restrict__ bs2,
    float* __restrict__ outpos)
{
    __shared__ float cat[64 + V_CH][NBLK];
    const int tid = threadIdx.x;
    const int n = blockIdx.x * NBLK + tid;
    const bool active = (n < N_NODES);
    const int nc = active ? n : 0;

    float s[64];
    {
        const float* p = ns + (size_t)nc * S_DIM;
        #pragma unroll
        for (int i = 0; i < 16; ++i) {
            float4 v4 = *reinterpret_cast<const float4*>(p + 4 * i);
            s[4 * i] = v4.x; s[4 * i + 1] = v4.y; s[4 * i + 2] = v4.z; s[4 * i + 3] = v4.w;
        }
    }
    float vv[48];
    {
        const float* p = vec + (size_t)nc * (V_CH * 3);
        #pragma unroll
        for (int i = 0; i < 12; ++i) {
            float4 v4 = *reinterpret_cast<const float4*>(p + 4 * i);
            vv[4 * i] = v4.x; vv[4 * i + 1] = v4.y; vv[4 * i + 2] = v4.z; vv[4 * i + 3] = v4.w;
        }
    }

    gvp_step<V_CH, true>(s, vv, Wh0, Wu0, Ws0, bs0, cat, tid);
    gvp_step<V_CH, true>(s, vv, Wh1, Wu1, Ws1, bs1, cat, tid);
    gvp_step<1, false>(s, vv, Wh2, Wu2, Ws2, bs2, cat, tid);

    if (active) {
        outpos[(size_t)n * 3 + 0] = pos[(size_t)n * 3 + 0] + vv[0];
        outpos[(size_t)n * 3 + 1] = pos[(size_t)n * 3 + 1] + vv[1];
        outpos[(size_t)n * 3 + 2] = pos[(size_t)n * 3 + 2] + vv[2];
    }
}

extern "C" void kernel_launch(void* const* d_in, const int* in_sizes, int n_in,
                              void* d_out, int out_size, void* d_ws, size_t ws_size,
                              hipStream_t stream) {
    const float* ns  = (const float*)d_in[0];
    const float* pos = (const float*)d_in[1];
    const float* vec = (const float*)d_in[2];
    const float* ef  = (const float*)d_in[3];
    const float* dd  = (const float*)d_in[4];
    const int*   src = (const int*)d_in[5];
    const int*   dst = (const int*)d_in[6];
    const float* W1  = (const float*)d_in[7];
    const float* b1  = (const float*)d_in[8];
    const float* W2  = (const float*)d_in[9];
    const float* b2  = (const float*)d_in[10];
    const float* lng = (const float*)d_in[11];
    const float* lnb = (const float*)d_in[12];
    const float* Wh0 = (const float*)d_in[13];
    const float* Wu0 = (const float*)d_in[14];
    const float* Ws0 = (const float*)d_in[15];
    const float* bs0 = (const float*)d_in[16];
    const float* Wh1 = (const float*)d_in[17];
    const float* Wu1 = (const float*)d_in[18];
    const float* Ws1 = (const float*)d_in[19];
    const float* bs1 = (const float*)d_in[20];
    const float* Wh2 = (const float*)d_in[21];
    const float* Wu2 = (const float*)d_in[22];
    const float* Ws2 = (const float*)d_in[23];
    const float* bs2 = (const float*)d_in[24];

    float* out     = (float*)d_out;
    float* out_pos = out + (size_t)N_EDGES * F_DIM;

    edge_kernel<<<EDGE_GRID, 256, 0, stream>>>(
        ns, ef, dd, src, dst, W1, b1, W2, b2, lng, lnb, out);
    node_kernel<<<(N_NODES + NBLK - 1) / NBLK, NBLK, 0, stream>>>(
        ns, pos, vec, Wh0, Wu0, Ws0, bs0, Wh1, Wu1, Ws1, bs1, Wh2, Wu2, Ws2, bs2, out_pos);
}